// Round 4
// baseline (100.685 us; speedup 1.0000x reference)
//
#include <hip/hip_runtime.h>

typedef __attribute__((ext_vector_type(8))) short short8;
typedef __attribute__((ext_vector_type(4))) unsigned short ushort4v;
typedef __attribute__((ext_vector_type(4))) int int4v;
typedef __attribute__((ext_vector_type(4))) float f32x4;

#define Mdim 64
#define Kdim 8192
#define Ndim 8192
#define GRP 128
#define NGRP 64
#define KSPLIT 8
#define NG2 (NGRP / KSPLIT)   // 8 groups per block
#define BN 64
#define PITCH 136             // 272B row pitch: 16B-aligned, odd 16B-granule stride

__device__ __forceinline__ unsigned short f2bf(float f) {
    unsigned int u = __builtin_bit_cast(unsigned int, f);
    u += 0x7FFFu + ((u >> 16) & 1u);   // round-to-nearest-even
    return (unsigned short)(u >> 16);
}
__device__ __forceinline__ float bf2f(unsigned short h) {
    unsigned int u = ((unsigned int)h) << 16;
    return __builtin_bit_cast(float, u);
}

// Build xh/xl (hi/lo bf16 split of x) and per-(group,m) sums xsum[g][m].
__global__ void prep_kernel(const float* __restrict__ x,
                            unsigned short* __restrict__ xh,
                            unsigned short* __restrict__ xl,
                            float* __restrict__ xsum) {
    const int tid = threadIdx.x;
    const int u = blockIdx.x * 8 + (tid >> 5);
    const int g = u & (NGRP - 1);
    const int m = u >> 6;
    const int lane = tid & 31;
    const int k = g * GRP + lane * 4;
    f32x4 v = *(const f32x4*)(x + (size_t)m * Kdim + k);
    ushort4v hv, lv;
    float s = 0.f;
#pragma unroll
    for (int i = 0; i < 4; ++i) {
        unsigned short h = f2bf(v[i]);
        hv[i] = h;
        lv[i] = f2bf(v[i] - bf2f(h));
        s += v[i];
    }
    *(ushort4v*)(xh + (size_t)m * Kdim + k) = hv;
    *(ushort4v*)(xl + (size_t)m * Kdim + k) = lv;
#pragma unroll
    for (int off = 16; off > 0; off >>= 1) s += __shfl_down(s, off, 32);
    if (lane == 0) xsum[g * Mdim + m] = s;
}

// Main: 1024 blocks = 128 n-tiles x 8 k-splits. 512 threads = 8 waves
// (4 m-tiles x 2 n-strips, wave = 16 rows x 32 cols). LDS holds ONLY q
// (double-buffered, 35 KB); x A-fragments load straight from global
// (already in fragment layout, L1/L2-resident). One barrier per group.
__launch_bounds__(512, 4)
__global__ void qlin_kernel(const unsigned short* __restrict__ xh,
                            const unsigned short* __restrict__ xl,
                            const int* __restrict__ qw,
                            const float* __restrict__ scales,
                            const float* __restrict__ zeros,
                            const float* __restrict__ xsum,
                            float* __restrict__ pout) {
    __shared__ unsigned short lq[2][BN][PITCH];

    const int tid = threadIdx.x;
    const int kh = blockIdx.x & (KSPLIT - 1);
    const int n0 = (blockIdx.x >> 3) * BN;
    const int g0 = kh * NG2;

    const int w = tid >> 6;
    const int mt = w >> 1;        // 0..3: 16-row m-tile
    const int wn = w & 1;         // 0..1: 32-col n-strip
    const int l = tid & 63;
    const int lcol = l & 15;
    const int lhi = l >> 4;

    // q staging: thread covers k-rows {2qp,2qp+1,64+2qp,64+2qp+1} x cols 4qc..+3
    const int qp = tid >> 4;      // 0..31
    const int qc = tid & 15;      // 0..15

    const int col0 = n0 + wn * 32 + lcol;
    const int col1 = col0 + 16;
    const int xrow = mt * 16 + lcol;    // A-operand row
    const int orow = mt * 16 + lhi * 4; // C row base

    int4v qa, qb, qcv, qd;
    float s0n, s1n, z0n, z1n;
    f32x4 xsn;

    auto LOADQ = [&](int g) {
        const size_t k0 = (size_t)g * GRP;
        const int ncol = n0 + 4 * qc;
        qa  = __builtin_nontemporal_load((const int4v*)(qw + (k0 + 2 * qp) * Ndim + ncol));
        qb  = __builtin_nontemporal_load((const int4v*)(qw + (k0 + 2 * qp + 1) * Ndim + ncol));
        qcv = __builtin_nontemporal_load((const int4v*)(qw + (k0 + 64 + 2 * qp) * Ndim + ncol));
        qd  = __builtin_nontemporal_load((const int4v*)(qw + (k0 + 64 + 2 * qp + 1) * Ndim + ncol));
        s0n = scales[(size_t)g * Ndim + col0];
        s1n = scales[(size_t)g * Ndim + col1];
        z0n = zeros[(size_t)g * Ndim + col0];
        z1n = zeros[(size_t)g * Ndim + col1];
        xsn = *(const f32x4*)(xsum + g * Mdim + orow);
    };
    auto WRITEQ = [&](int b) {
#pragma unroll
        for (int j = 0; j < 4; ++j) {
            unsigned int lo = (unsigned int)f2bf((float)qa[j]) |
                              ((unsigned int)f2bf((float)qb[j]) << 16);
            unsigned int hi = (unsigned int)f2bf((float)qcv[j]) |
                              ((unsigned int)f2bf((float)qd[j]) << 16);
            *(unsigned int*)&lq[b][4 * qc + j][2 * qp] = lo;
            *(unsigned int*)&lq[b][4 * qc + j][64 + 2 * qp] = hi;
        }
    };

    f32x4 acc0 = {0.f, 0.f, 0.f, 0.f}, acc1 = {0.f, 0.f, 0.f, 0.f};
    f32x4 p0 = {0.f, 0.f, 0.f, 0.f}, p1 = {0.f, 0.f, 0.f, 0.f};
    float s0c, s1c, z0c, z1c;
    f32x4 xsc;

    LOADQ(g0);
    WRITEQ(0);
    s0c = s0n; s1c = s1n; z0c = z0n; z1c = z1n; xsc = xsn;
    __syncthreads();

    for (int g = 0; g < NG2; ++g) {
        const int cb = g & 1;
        if (g + 1 < NG2) LOADQ(g0 + g + 1);
        const size_t ka = (size_t)(g0 + g) * GRP + lhi * 8;
#pragma unroll
        for (int ks = 0; ks < 4; ++ks) {
            short8 ah = *(const short8*)(xh + (size_t)xrow * Kdim + ka + ks * 32);
            short8 al = *(const short8*)(xl + (size_t)xrow * Kdim + ka + ks * 32);
            short8 b0 = *(const short8*)&lq[cb][wn * 32 + lcol][ks * 32 + lhi * 8];
            short8 b1 = *(const short8*)&lq[cb][wn * 32 + 16 + lcol][ks * 32 + lhi * 8];
            p0 = __builtin_amdgcn_mfma_f32_16x16x32_bf16(ah, b0, p0, 0, 0, 0);
            p0 = __builtin_amdgcn_mfma_f32_16x16x32_bf16(al, b0, p0, 0, 0, 0);
            p1 = __builtin_amdgcn_mfma_f32_16x16x32_bf16(ah, b1, p1, 0, 0, 0);
            p1 = __builtin_amdgcn_mfma_f32_16x16x32_bf16(al, b1, p1, 0, 0, 0);
        }
#pragma unroll
        for (int r = 0; r < 4; ++r) {
            acc0[r] += s0c * (p0[r] - z0c * xsc[r]); p0[r] = 0.f;
            acc1[r] += s1c * (p1[r] - z1c * xsc[r]); p1[r] = 0.f;
        }
        if (g + 1 < NG2) {
            WRITEQ(cb ^ 1);
            s0c = s0n; s1c = s1n; z0c = z0n; z1c = z1n; xsc = xsn;
            __syncthreads();
        }
    }

    const size_t ob = (size_t)kh * Mdim * Ndim;
#pragma unroll
    for (int r = 0; r < 4; ++r) {
        pout[ob + (size_t)(orow + r) * Ndim + col0] = acc0[r];
        pout[ob + (size_t)(orow + r) * Ndim + col1] = acc1[r];
    }
}

// out = sum of 8 partials + bias
__global__ void reduce_kernel(const float* __restrict__ pout,
                              const float* __restrict__ bias,
                              float* __restrict__ out) {
    const size_t e = ((size_t)blockIdx.x * 256 + threadIdx.x) * 4;
    const int n = (int)(e & (Ndim - 1));
    f32x4 a = *(const f32x4*)(bias + n);
#pragma unroll
    for (int s = 0; s < KSPLIT; ++s) {
        f32x4 ppart = *(const f32x4*)(pout + (size_t)s * Mdim * Ndim + e);
#pragma unroll
        for (int r = 0; r < 4; ++r) a[r] += ppart[r];
    }
    *(f32x4*)(out + e) = a;
}

extern "C" void kernel_launch(void* const* d_in, const int* in_sizes, int n_in,
                              void* d_out, int out_size, void* d_ws, size_t ws_size,
                              hipStream_t stream) {
    const float* x = (const float*)d_in[0];
    const int* qw = (const int*)d_in[1];
    const float* scales = (const float*)d_in[2];
    const float* zeros = (const float*)d_in[3];
    const float* bias = (const float*)d_in[4];

    unsigned short* xh = (unsigned short*)d_ws;
    unsigned short* xl = xh + (size_t)Mdim * Kdim;
    float* xsum = (float*)(xl + (size_t)Mdim * Kdim);
    float* pout = xsum + NGRP * Mdim;
    float* out = (float*)d_out;

    prep_kernel<<<512, 256, 0, stream>>>(x, xh, xl, xsum);
    qlin_kernel<<<(Ndim / BN) * KSPLIT, 512, 0, stream>>>(xh, xl, qw, scales, zeros, xsum, pout);
    reduce_kernel<<<(Mdim * Ndim / 4) / 256, 256, 0, stream>>>(pout, bias, out);
}